// Round 3
// baseline (190.880 us; speedup 1.0000x reference)
//
#include <hip/hip_runtime.h>

// DepthLossWithMask: loss = sum(|output - label0| * label1) / count(label0 != 0)
// N = 16*15*256*256 = 15,728,640 floats -> n4 = 3,932,160 float4.
//
// History:
//  R3: atomic-free two-stage reduction, stage1 ~70us.
//  R4 FAILED: launch_bounds + separated load loops: compiler re-interleaved
//     (VGPR 52->36, flat).
//  R5 FAILED: sched_barrier(0) fence: compiler still serialized (VGPR 28,
//     flat). KEY DATA: occupancy 29%->58% across rounds with ZERO speedup,
//     but waves x per-wave-MLP product was constant. Effective read rate
//     pinned at ~2.8 TB/s =~ 11 GB/s/CU =~ 90% of m13 copy's read component.
//  R6 (this): decisive test of T-occ vs T-cap. Persistent grid-stride:
//     1920 blocks (<=8/CU, ALL resident, zero turnover, ~30 waves/CU) x
//     2-way stream interleave = 6 independent loads/iter/wave, exact
//     divisibility (n4 = 1920*256*2*4) -> no guards, no selects.
//     >=4x the waves*MLP product of any prior round. If flat again ->
//     per-CU read-delivery cap confirmed -> roofline.

#define REDUCE_THREADS 256
#define S1_BLOCKS 1920   // n4 % (1920*256*2) == 0 -> 4 exact double-iterations

struct Partial {
    float s;
    unsigned int c;
};

__device__ __forceinline__ void accum4(const float4& o, const float4& a,
                                       const float4& w, float& sum,
                                       unsigned int& cnt) {
    sum += fabsf(o.x - a.x) * w.x;
    sum += fabsf(o.y - a.y) * w.y;
    sum += fabsf(o.z - a.z) * w.z;
    sum += fabsf(o.w - a.w) * w.w;
    cnt += (a.x != 0.0f) + (a.y != 0.0f) + (a.z != 0.0f) + (a.w != 0.0f);
}

// EXACT2: n4 divisible by 2*gridDim*blockDim -> guard-free 2-way interleave.
template <bool EXACT2>
__global__ __launch_bounds__(REDUCE_THREADS)
void depth_loss_stage1(const float4* __restrict__ out,
                       const float4* __restrict__ l0,
                       const float4* __restrict__ l1,
                       Partial* __restrict__ partials,
                       int n4) {
    const int stride = gridDim.x * REDUCE_THREADS;
    int i = blockIdx.x * REDUCE_THREADS + threadIdx.x;

    float sum = 0.0f;
    unsigned int cnt = 0;

    if constexpr (EXACT2) {
        for (; i < n4; i += 2 * stride) {
            // 6 independent 1KB wave-loads in flight before any use.
            float4 o0 = out[i];
            float4 a0 = l0[i];
            float4 w0 = l1[i];
            float4 o1 = out[i + stride];
            float4 a1 = l0[i + stride];
            float4 w1 = l1[i + stride];
            accum4(o0, a0, w0, sum, cnt);
            accum4(o1, a1, w1, sum, cnt);
        }
    } else {
        for (; i < n4; i += stride) {
            float4 o0 = out[i];
            float4 a0 = l0[i];
            float4 w0 = l1[i];
            accum4(o0, a0, w0, sum, cnt);
        }
    }

    // wave-64 butterfly reduce
    #pragma unroll
    for (int off = 32; off > 0; off >>= 1) {
        sum += __shfl_down(sum, off, 64);
        cnt += __shfl_down(cnt, off, 64);
    }

    __shared__ float        sv[REDUCE_THREADS / 64];
    __shared__ unsigned int sc[REDUCE_THREADS / 64];
    int lane = threadIdx.x & 63;
    int wid  = threadIdx.x >> 6;
    if (lane == 0) { sv[wid] = sum; sc[wid] = cnt; }
    __syncthreads();

    if (threadIdx.x == 0) {
        float bs = 0.0f;
        unsigned int bc = 0;
        #pragma unroll
        for (int i2 = 0; i2 < REDUCE_THREADS / 64; ++i2) { bs += sv[i2]; bc += sc[i2]; }
        Partial p; p.s = bs; p.c = bc;
        partials[blockIdx.x] = p;   // plain 8B store, no contention
    }
}

__global__ __launch_bounds__(REDUCE_THREADS)
void depth_loss_stage2(const Partial* __restrict__ partials,
                       int nblocks,
                       float* __restrict__ out) {
    double sum = 0.0;
    unsigned int cnt = 0;
    for (int i = threadIdx.x; i < nblocks; i += REDUCE_THREADS) {
        Partial p = partials[i];
        sum += (double)p.s;
        cnt += p.c;
    }

    #pragma unroll
    for (int off = 32; off > 0; off >>= 1) {
        sum += __shfl_down(sum, off, 64);
        cnt += __shfl_down(cnt, off, 64);
    }

    __shared__ double       sv[REDUCE_THREADS / 64];
    __shared__ unsigned int sc[REDUCE_THREADS / 64];
    int lane = threadIdx.x & 63;
    int wid  = threadIdx.x >> 6;
    if (lane == 0) { sv[wid] = sum; sc[wid] = cnt; }
    __syncthreads();

    if (threadIdx.x == 0) {
        double bs = 0.0;
        unsigned int bc = 0;
        #pragma unroll
        for (int i = 0; i < REDUCE_THREADS / 64; ++i) { bs += sv[i]; bc += sc[i]; }
        out[0] = (bc == 0) ? 0.0f : (float)(bs / (double)bc);
    }
}

extern "C" void kernel_launch(void* const* d_in, const int* in_sizes, int n_in,
                              void* d_out, int out_size, void* d_ws, size_t ws_size,
                              hipStream_t stream) {
    const float* output = (const float*)d_in[0];
    const float* label0 = (const float*)d_in[1];
    const float* label1 = (const float*)d_in[2];
    int n = in_sizes[0];           // 15,728,640
    int n4 = n >> 2;               // 3,932,160 float4

    Partial* partials = (Partial*)d_ws;             // 1920*8 = 15 KB, all written

    if ((n4 % (S1_BLOCKS * REDUCE_THREADS * 2)) == 0) {
        depth_loss_stage1<true><<<S1_BLOCKS, REDUCE_THREADS, 0, stream>>>(
            (const float4*)output, (const float4*)label0, (const float4*)label1,
            partials, n4);
    } else {
        depth_loss_stage1<false><<<S1_BLOCKS, REDUCE_THREADS, 0, stream>>>(
            (const float4*)output, (const float4*)label0, (const float4*)label1,
            partials, n4);
    }

    depth_loss_stage2<<<1, REDUCE_THREADS, 0, stream>>>(
        partials, S1_BLOCKS, (float*)d_out);
}

// Round 4
// 189.755 us; speedup vs baseline: 1.0059x; 1.0059x over previous
//
#include <hip/hip_runtime.h>

// DepthLossWithMask: loss = sum(|output - label0| * label1) / count(label0 != 0)
// N = 16*15*256*256 = 15,728,640 floats -> n4 = 3,932,160 float4.
//
// History:
//  R3: atomic-free two-stage reduction, stage1 ~70us (~2.8 TB/s delivered).
//  R4 FAILED: launch_bounds + separated load loops -> compiler re-serialized
//     (VGPR 52->36, flat).
//  R5 FAILED: sched_barrier(0) -> still serialized (VGPR 28, flat).
//  R6 VOID: persistent grid 2-way interleave -> VGPR 20 (!) -- compiler again
//     rolled loads into load->wait->use. The T-occ (MLP) theory was never
//     actually tested at ISA level. Invariant so far: occupancy 29-58%,
//     VGPR 20-52, grid 1920-3840 => ALL pinned at 67-71us (~11 GB/s/CU).
//  R7 (this): inline-asm global_load_dwordx4 -- the compiler cannot reorder
//     or sink asm volatile blocks and does not track their vmcnt; we place
//     the single s_waitcnt vmcnt(0) ourselves ("memory" clobber +
//     sched_barrier(0) per guide rule #18 to stop consumer hoisting).
//     18 loads (18 KB) genuinely in flight per wave; ~20 waves/CU resident
//     -> ~360 KB/CU outstanding vs ~21 KB needed for 6 TB/s @ 900ns.
//     Decisive: VGPR ~100+ & flat => real per-CU delivery cap => roofline.

#define REDUCE_THREADS 256
#define EPT 6                 // float4 triples per thread
#define S1_BLOCKS 2560        // 2560*256*6 == 3,932,160 == n4 exactly

typedef float f32x4 __attribute__((ext_vector_type(4)));

struct Partial {
    float s;
    unsigned int c;
};

__device__ __forceinline__ f32x4 gload4(const f32x4* p) {
    f32x4 r;
    // volatile: cannot be elided, sunk, or reordered vs other volatile asm.
    asm volatile("global_load_dwordx4 %0, %1, off" : "=v"(r) : "v"(p));
    return r;
}

__device__ __forceinline__ void accum4(const f32x4& o, const f32x4& a,
                                       const f32x4& w, float& sum,
                                       unsigned int& cnt) {
    sum += fabsf(o[0] - a[0]) * w[0];
    sum += fabsf(o[1] - a[1]) * w[1];
    sum += fabsf(o[2] - a[2]) * w[2];
    sum += fabsf(o[3] - a[3]) * w[3];
    cnt += (a[0] != 0.0f) + (a[1] != 0.0f) + (a[2] != 0.0f) + (a[3] != 0.0f);
}

template <bool EXACT>
__global__ __launch_bounds__(REDUCE_THREADS)
void depth_loss_stage1(const f32x4* __restrict__ out,
                       const f32x4* __restrict__ l0,
                       const f32x4* __restrict__ l1,
                       Partial* __restrict__ partials,
                       int n4) {
    float sum = 0.0f;
    unsigned int cnt = 0;

    if constexpr (EXACT) {
        const int base = blockIdx.x * (REDUCE_THREADS * EPT) + threadIdx.x;

        f32x4 o[EPT], a[EPT], w[EPT];
        // 18 asm-volatile loads issued back-to-back: 18 KB in flight/wave.
        #pragma unroll
        for (int k = 0; k < EPT; ++k) {
            const int i = base + k * REDUCE_THREADS;
            o[k] = gload4(&out[i]);
            a[k] = gload4(&l0[i]);
            w[k] = gload4(&l1[i]);
        }
        // Single explicit drain; compiler doesn't know the asm loads'
        // counters, so it cannot insert earlier waits. memory clobber +
        // sched_barrier(0) keep consumers below this point (rule #18).
        asm volatile("s_waitcnt vmcnt(0)" ::: "memory");
        __builtin_amdgcn_sched_barrier(0);

        #pragma unroll
        for (int k = 0; k < EPT; ++k) accum4(o[k], a[k], w[k], sum, cnt);
    } else {
        const int stride = gridDim.x * REDUCE_THREADS;
        for (int i = blockIdx.x * REDUCE_THREADS + threadIdx.x; i < n4;
             i += stride) {
            f32x4 o0 = out[i], a0 = l0[i], w0 = l1[i];
            accum4(o0, a0, w0, sum, cnt);
        }
    }

    // wave-64 butterfly reduce
    #pragma unroll
    for (int off = 32; off > 0; off >>= 1) {
        sum += __shfl_down(sum, off, 64);
        cnt += __shfl_down(cnt, off, 64);
    }

    __shared__ float        sv[REDUCE_THREADS / 64];
    __shared__ unsigned int sc[REDUCE_THREADS / 64];
    int lane = threadIdx.x & 63;
    int wid  = threadIdx.x >> 6;
    if (lane == 0) { sv[wid] = sum; sc[wid] = cnt; }
    __syncthreads();

    if (threadIdx.x == 0) {
        float bs = 0.0f;
        unsigned int bc = 0;
        #pragma unroll
        for (int i2 = 0; i2 < REDUCE_THREADS / 64; ++i2) { bs += sv[i2]; bc += sc[i2]; }
        Partial p; p.s = bs; p.c = bc;
        partials[blockIdx.x] = p;   // plain 8B store, no contention
    }
}

__global__ __launch_bounds__(REDUCE_THREADS)
void depth_loss_stage2(const Partial* __restrict__ partials,
                       int nblocks,
                       float* __restrict__ out) {
    double sum = 0.0;
    unsigned int cnt = 0;
    for (int i = threadIdx.x; i < nblocks; i += REDUCE_THREADS) {
        Partial p = partials[i];
        sum += (double)p.s;
        cnt += p.c;
    }

    #pragma unroll
    for (int off = 32; off > 0; off >>= 1) {
        sum += __shfl_down(sum, off, 64);
        cnt += __shfl_down(cnt, off, 64);
    }

    __shared__ double       sv[REDUCE_THREADS / 64];
    __shared__ unsigned int sc[REDUCE_THREADS / 64];
    int lane = threadIdx.x & 63;
    int wid  = threadIdx.x >> 6;
    if (lane == 0) { sv[wid] = sum; sc[wid] = cnt; }
    __syncthreads();

    if (threadIdx.x == 0) {
        double bs = 0.0;
        unsigned int bc = 0;
        #pragma unroll
        for (int i = 0; i < REDUCE_THREADS / 64; ++i) { bs += sv[i]; bc += sc[i]; }
        out[0] = (bc == 0) ? 0.0f : (float)(bs / (double)bc);
    }
}

extern "C" void kernel_launch(void* const* d_in, const int* in_sizes, int n_in,
                              void* d_out, int out_size, void* d_ws, size_t ws_size,
                              hipStream_t stream) {
    const float* output = (const float*)d_in[0];
    const float* label0 = (const float*)d_in[1];
    const float* label1 = (const float*)d_in[2];
    int n = in_sizes[0];           // 15,728,640
    int n4 = n >> 2;               // 3,932,160 float4

    Partial* partials = (Partial*)d_ws;

    if (n4 == S1_BLOCKS * REDUCE_THREADS * EPT) {
        depth_loss_stage1<true><<<S1_BLOCKS, REDUCE_THREADS, 0, stream>>>(
            (const f32x4*)output, (const f32x4*)label0, (const f32x4*)label1,
            partials, n4);
        depth_loss_stage2<<<1, REDUCE_THREADS, 0, stream>>>(
            partials, S1_BLOCKS, (float*)d_out);
    } else {
        int blocks = 2048;
        depth_loss_stage1<false><<<blocks, REDUCE_THREADS, 0, stream>>>(
            (const f32x4*)output, (const f32x4*)label0, (const f32x4*)label1,
            partials, n4);
        depth_loss_stage2<<<1, REDUCE_THREADS, 0, stream>>>(
            partials, blocks, (float*)d_out);
    }
}

// Round 5
// 172.327 us; speedup vs baseline: 1.1077x; 1.1011x over previous
//
#include <hip/hip_runtime.h>

// DepthLossWithMask: loss = sum(|output - label0| * label1) / count(label0 != 0)
// N = 16*15*256*256 = 15,728,640 floats -> n4 = 3,932,160 float4.
//
// History:
//  R3: atomic-free two-stage reduction, stage1 ~70us (~2.8 TB/s delivered).
//  R4/R5/R6/R7 ALL FLAT at 67-71us across: occupancy 29-58%, VGPR 20-52,
//     grid 1920-3840, source-level MLP forcing (separated loops,
//     sched_barrier, manual interleave, inline-asm loads+own vmcnt).
//  KEY REFRAME (R8): Little's law says MLP was never binding -- even the
//     serialized model at 17 waves/CU predicts ~85 GB/s/CU vs observed 11.
//     The cap is read-return THROUGHPUT, not concurrency. All measured
//     kernels on this chip show read-component <= ~3.15 TB/s; we stream
//     189MB with ZERO reuse through L2/L3, paying allocate+evict on every
//     line (FETCH=92MB: half the stream is bouncing through L3 from the
//     harness re-poison, splitting the L2-miss path two ways).
//  R8 (this): __builtin_nontemporal_load on all three streams (nt bit ->
//     L2 no-allocate streaming). Needs no scheduler cooperation -- cannot
//     be silently undone like R4-R7. If FETCH rises to ~189MB and dur is
//     still ~68us, the ~2.8 TB/s read cap is source-independent => roofline.

#define REDUCE_THREADS 256
#define S1_BLOCKS 1920   // 3,932,160 / (1920*256) = 8 exact iterations

typedef float f32x4 __attribute__((ext_vector_type(4)));

struct Partial {
    float s;
    unsigned int c;
};

__global__ __launch_bounds__(REDUCE_THREADS)
void depth_loss_stage1(const f32x4* __restrict__ out,
                       const f32x4* __restrict__ l0,
                       const f32x4* __restrict__ l1,
                       Partial* __restrict__ partials,
                       int n4) {
    const int stride = gridDim.x * REDUCE_THREADS;

    float sum = 0.0f;
    unsigned int cnt = 0;

    for (int i = blockIdx.x * REDUCE_THREADS + threadIdx.x; i < n4;
         i += stride) {
        // Non-temporal: global_load_dwordx4 with nt -- no L2 allocate.
        // Streaming data with zero reuse shouldn't displace cache lines
        // or pay the allocate/evict round-trip.
        f32x4 o = __builtin_nontemporal_load(&out[i]);
        f32x4 a = __builtin_nontemporal_load(&l0[i]);
        f32x4 w = __builtin_nontemporal_load(&l1[i]);

        sum += fabsf(o[0] - a[0]) * w[0];
        sum += fabsf(o[1] - a[1]) * w[1];
        sum += fabsf(o[2] - a[2]) * w[2];
        sum += fabsf(o[3] - a[3]) * w[3];
        cnt += (a[0] != 0.0f) + (a[1] != 0.0f) +
               (a[2] != 0.0f) + (a[3] != 0.0f);
    }

    // wave-64 butterfly reduce
    #pragma unroll
    for (int off = 32; off > 0; off >>= 1) {
        sum += __shfl_down(sum, off, 64);
        cnt += __shfl_down(cnt, off, 64);
    }

    __shared__ float        sv[REDUCE_THREADS / 64];
    __shared__ unsigned int sc[REDUCE_THREADS / 64];
    int lane = threadIdx.x & 63;
    int wid  = threadIdx.x >> 6;
    if (lane == 0) { sv[wid] = sum; sc[wid] = cnt; }
    __syncthreads();

    if (threadIdx.x == 0) {
        float bs = 0.0f;
        unsigned int bc = 0;
        #pragma unroll
        for (int i2 = 0; i2 < REDUCE_THREADS / 64; ++i2) { bs += sv[i2]; bc += sc[i2]; }
        Partial p; p.s = bs; p.c = bc;
        partials[blockIdx.x] = p;   // plain 8B store, no contention
    }
}

__global__ __launch_bounds__(REDUCE_THREADS)
void depth_loss_stage2(const Partial* __restrict__ partials,
                       int nblocks,
                       float* __restrict__ out) {
    double sum = 0.0;
    unsigned int cnt = 0;
    for (int i = threadIdx.x; i < nblocks; i += REDUCE_THREADS) {
        Partial p = partials[i];
        sum += (double)p.s;
        cnt += p.c;
    }

    #pragma unroll
    for (int off = 32; off > 0; off >>= 1) {
        sum += __shfl_down(sum, off, 64);
        cnt += __shfl_down(cnt, off, 64);
    }

    __shared__ double       sv[REDUCE_THREADS / 64];
    __shared__ unsigned int sc[REDUCE_THREADS / 64];
    int lane = threadIdx.x & 63;
    int wid  = threadIdx.x >> 6;
    if (lane == 0) { sv[wid] = sum; sc[wid] = cnt; }
    __syncthreads();

    if (threadIdx.x == 0) {
        double bs = 0.0;
        unsigned int bc = 0;
        #pragma unroll
        for (int i = 0; i < REDUCE_THREADS / 64; ++i) { bs += sv[i]; bc += sc[i]; }
        out[0] = (bc == 0) ? 0.0f : (float)(bs / (double)bc);
    }
}

extern "C" void kernel_launch(void* const* d_in, const int* in_sizes, int n_in,
                              void* d_out, int out_size, void* d_ws, size_t ws_size,
                              hipStream_t stream) {
    const float* output = (const float*)d_in[0];
    const float* label0 = (const float*)d_in[1];
    const float* label1 = (const float*)d_in[2];
    int n = in_sizes[0];           // 15,728,640
    int n4 = n >> 2;               // 3,932,160 float4

    Partial* partials = (Partial*)d_ws;   // 1920*8 = 15 KB, all written

    depth_loss_stage1<<<S1_BLOCKS, REDUCE_THREADS, 0, stream>>>(
        (const f32x4*)output, (const f32x4*)label0, (const f32x4*)label1,
        partials, n4);

    depth_loss_stage2<<<1, REDUCE_THREADS, 0, stream>>>(
        partials, S1_BLOCKS, (float*)d_out);
}

// Round 7
// 170.767 us; speedup vs baseline: 1.1178x; 1.0091x over previous
//
#include <hip/hip_runtime.h>

// DepthLossWithMask: loss = sum(|output - label0| * label1) / count(label0 != 0)
// N = 16*15*256*256 = 15,728,640 floats -> n4 = 3,932,160 float4.
//
// History:
//  R3-R7: all MLP/occupancy manipulations FLAT at 67-71us (~2.8 TB/s).
//  R8 WIN: __builtin_nontemporal_load (L2 no-allocate) broke the cap:
//     stage1 dropped below the 42us harness fills (>=4.5 TB/s), total
//     187->172us. The old ~2.8 TB/s cap was L2/L3 allocate-evict drag on
//     a zero-reuse stream, NOT a HW read ceiling.
//  DECOMPOSITION: timed region = ~3x 42us fillBufferAligned (256MiB
//     harness re-poison @ 6.4 TB/s write -- untouchable) + stage1 + stage2.
//     Remaining recoverable: stage1 ~40us -> ~30us (6.3 TB/s read) + crumbs.
//  R9 COMPILE FAIL: __builtin_nontemporal_store rejects struct* -- reverted
//     to plain 8B partial store (it was never load-path-relevant).
//  R10 (this): nt loads + guard-free 2-way interleaved persistent grid
//     (1920 blocks x 256 thr: n4/491520 = 8 exact iters, 4 double-iters).
//     With the allocate drag gone, issue-side MLP can pay again.

#define REDUCE_THREADS 256
#define S1_BLOCKS 1920   // 3,932,160 / (1920*256) = 8 exact -> 4 double-iters

typedef float f32x4 __attribute__((ext_vector_type(4)));

struct Partial {
    float s;
    unsigned int c;
};

__device__ __forceinline__ void accum4(const f32x4& o, const f32x4& a,
                                       const f32x4& w, float& sum,
                                       unsigned int& cnt) {
    sum += fabsf(o[0] - a[0]) * w[0];
    sum += fabsf(o[1] - a[1]) * w[1];
    sum += fabsf(o[2] - a[2]) * w[2];
    sum += fabsf(o[3] - a[3]) * w[3];
    cnt += (a[0] != 0.0f) + (a[1] != 0.0f) + (a[2] != 0.0f) + (a[3] != 0.0f);
}

template <bool EXACT2>
__global__ __launch_bounds__(REDUCE_THREADS)
void depth_loss_stage1(const f32x4* __restrict__ out,
                       const f32x4* __restrict__ l0,
                       const f32x4* __restrict__ l1,
                       Partial* __restrict__ partials,
                       int n4) {
    const int stride = gridDim.x * REDUCE_THREADS;
    int i = blockIdx.x * REDUCE_THREADS + threadIdx.x;

    float sum = 0.0f;
    unsigned int cnt = 0;

    if constexpr (EXACT2) {
        #pragma unroll 2
        for (; i < n4; i += 2 * stride) {
            const int j = i + stride;
            // 6 nt loads (no L2 allocate) issued for two iterations before
            // either is consumed: up to 6 KB/wave in flight on the pure-HBM
            // path now that the allocate/evict serialization is gone.
            f32x4 o0 = __builtin_nontemporal_load(&out[i]);
            f32x4 a0 = __builtin_nontemporal_load(&l0[i]);
            f32x4 w0 = __builtin_nontemporal_load(&l1[i]);
            f32x4 o1 = __builtin_nontemporal_load(&out[j]);
            f32x4 a1 = __builtin_nontemporal_load(&l0[j]);
            f32x4 w1 = __builtin_nontemporal_load(&l1[j]);
            accum4(o0, a0, w0, sum, cnt);
            accum4(o1, a1, w1, sum, cnt);
        }
    } else {
        for (; i < n4; i += stride) {
            f32x4 o = __builtin_nontemporal_load(&out[i]);
            f32x4 a = __builtin_nontemporal_load(&l0[i]);
            f32x4 w = __builtin_nontemporal_load(&l1[i]);
            accum4(o, a, w, sum, cnt);
        }
    }

    // wave-64 butterfly reduce
    #pragma unroll
    for (int off = 32; off > 0; off >>= 1) {
        sum += __shfl_down(sum, off, 64);
        cnt += __shfl_down(cnt, off, 64);
    }

    __shared__ float        sv[REDUCE_THREADS / 64];
    __shared__ unsigned int sc[REDUCE_THREADS / 64];
    int lane = threadIdx.x & 63;
    int wid  = threadIdx.x >> 6;
    if (lane == 0) { sv[wid] = sum; sc[wid] = cnt; }
    __syncthreads();

    if (threadIdx.x == 0) {
        float bs = 0.0f;
        unsigned int bc = 0;
        #pragma unroll
        for (int i2 = 0; i2 < REDUCE_THREADS / 64; ++i2) { bs += sv[i2]; bc += sc[i2]; }
        Partial p; p.s = bs; p.c = bc;
        partials[blockIdx.x] = p;   // plain 8B store, no contention
    }
}

__global__ __launch_bounds__(REDUCE_THREADS)
void depth_loss_stage2(const Partial* __restrict__ partials,
                       int nblocks,
                       float* __restrict__ out) {
    double sum = 0.0;
    unsigned int cnt = 0;
    for (int i = threadIdx.x; i < nblocks; i += REDUCE_THREADS) {
        Partial p = partials[i];
        sum += (double)p.s;
        cnt += p.c;
    }

    #pragma unroll
    for (int off = 32; off > 0; off >>= 1) {
        sum += __shfl_down(sum, off, 64);
        cnt += __shfl_down(cnt, off, 64);
    }

    __shared__ double       sv[REDUCE_THREADS / 64];
    __shared__ unsigned int sc[REDUCE_THREADS / 64];
    int lane = threadIdx.x & 63;
    int wid  = threadIdx.x >> 6;
    if (lane == 0) { sv[wid] = sum; sc[wid] = cnt; }
    __syncthreads();

    if (threadIdx.x == 0) {
        double bs = 0.0;
        unsigned int bc = 0;
        #pragma unroll
        for (int i = 0; i < REDUCE_THREADS / 64; ++i) { bs += sv[i]; bc += sc[i]; }
        out[0] = (bc == 0) ? 0.0f : (float)(bs / (double)bc);
    }
}

extern "C" void kernel_launch(void* const* d_in, const int* in_sizes, int n_in,
                              void* d_out, int out_size, void* d_ws, size_t ws_size,
                              hipStream_t stream) {
    const float* output = (const float*)d_in[0];
    const float* label0 = (const float*)d_in[1];
    const float* label1 = (const float*)d_in[2];
    int n = in_sizes[0];           // 15,728,640
    int n4 = n >> 2;               // 3,932,160 float4

    Partial* partials = (Partial*)d_ws;   // 1920*8 = 15 KB, all written

    if ((n4 % (S1_BLOCKS * REDUCE_THREADS * 2)) == 0) {
        depth_loss_stage1<true><<<S1_BLOCKS, REDUCE_THREADS, 0, stream>>>(
            (const f32x4*)output, (const f32x4*)label0, (const f32x4*)label1,
            partials, n4);
    } else {
        depth_loss_stage1<false><<<S1_BLOCKS, REDUCE_THREADS, 0, stream>>>(
            (const f32x4*)output, (const f32x4*)label0, (const f32x4*)label1,
            partials, n4);
    }

    depth_loss_stage2<<<1, REDUCE_THREADS, 0, stream>>>(
        partials, S1_BLOCKS, (float*)d_out);
}